// Round 1
// baseline (1786.674 us; speedup 1.0000x reference)
//
#include <hip/hip_runtime.h>

#define NN 50000
#define NE 800000
#define DIM 512
#define MLPH 200

// ---------------- CSR build ----------------
__global__ void k_hist(const int* __restrict__ dst, int* __restrict__ counts) {
    int e = blockIdx.x * blockDim.x + threadIdx.x;
    if (e < NE) atomicAdd(&counts[dst[e]], 1);
}

__global__ void k_scan(const int* __restrict__ counts, int* __restrict__ rowstart,
                       int* __restrict__ cursor) {
    __shared__ int sm[1024];
    __shared__ int carry;
    if (threadIdx.x == 0) carry = 0;
    __syncthreads();
    for (int base = 0; base < NN; base += 1024) {
        int i = base + threadIdx.x;
        int x = (i < NN) ? counts[i] : 0;
        sm[threadIdx.x] = x;
        __syncthreads();
        for (int off = 1; off < 1024; off <<= 1) {
            int v = (threadIdx.x >= (unsigned)off) ? sm[threadIdx.x - off] : 0;
            __syncthreads();
            sm[threadIdx.x] += v;
            __syncthreads();
        }
        int incl = sm[threadIdx.x];
        int excl = incl - x;
        if (i < NN) { rowstart[i] = carry + excl; cursor[i] = carry + excl; }
        __syncthreads();
        if (threadIdx.x == 1023) carry += incl;  // incl of last thread == chunk total
        __syncthreads();
    }
    if (threadIdx.x == 0) rowstart[NN] = carry;
}

__global__ void k_fill(const int* __restrict__ src, const int* __restrict__ dst,
                       int* __restrict__ cursor, int* __restrict__ adj) {
    int e = blockIdx.x * blockDim.x + threadIdx.x;
    if (e < NE) {
        int p = atomicAdd(&cursor[dst[e]], 1);
        adj[p] = src[e];
    }
}

// ---------------- aggregation: h_neigh = (sum_nbr h[nbr] + 2h) / (deg+2) ----------------
__global__ void k_agg(const float* __restrict__ h, const int* __restrict__ rowstart,
                      const int* __restrict__ adj, const int* __restrict__ counts,
                      float* __restrict__ out) {
    int node = blockIdx.x;
    int col = threadIdx.x;
    int s = rowstart[node], e = rowstart[node + 1];
    float acc = 2.0f * h[(size_t)node * DIM + col];
    for (int i = s; i < e; i++) {
        int nbr = adj[i];
        acc += h[(size_t)nbr * DIM + col];
    }
    float inv = 1.0f / (float)(counts[node] + 2);
    out[(size_t)node * DIM + col] = acc * inv;
}

// ---------------- fp32 tiled GEMM: C[M,NCOLS] = A[M,512] @ B[512,NCOLS] + bias (+relu) ----------------
template <int NCOLS, bool RELU>
__global__ __launch_bounds__(256) void k_gemm(const float* __restrict__ A,
                                              const float* __restrict__ B,
                                              const float* __restrict__ bias,
                                              float* __restrict__ C, int M) {
    constexpr int K = 512;
    __shared__ float As[16][68];
    __shared__ float Bs[16][68];
    const int tid = threadIdx.x;
    const int row0 = blockIdx.x * 64;
    const int col0 = blockIdx.y * 64;
    const int tr = tid >> 4;   // 0..15
    const int tc = tid & 15;   // 0..15
    const int arow = tid >> 2; // 0..63
    const int akq = tid & 3;   // 0..3
    const int bkk = tid >> 4;  // 0..15
    const int bc = (tid & 15) * 4;

    float acc[4][4] = {};
    const bool a_ok = (row0 + arow) < M;
    const bool b_ok = (col0 + bc) < NCOLS;
    const float* Aptr = A + (size_t)(row0 + arow) * K + akq * 4;

    for (int k0 = 0; k0 < K; k0 += 16) {
        float4 av = a_ok ? *(const float4*)(Aptr + k0) : float4{0.f, 0.f, 0.f, 0.f};
        float4 bv = b_ok ? *(const float4*)(B + (size_t)(k0 + bkk) * NCOLS + col0 + bc)
                         : float4{0.f, 0.f, 0.f, 0.f};
        __syncthreads();
        As[akq * 4 + 0][arow] = av.x;
        As[akq * 4 + 1][arow] = av.y;
        As[akq * 4 + 2][arow] = av.z;
        As[akq * 4 + 3][arow] = av.w;
        *(float4*)&Bs[bkk][bc] = bv;
        __syncthreads();
#pragma unroll
        for (int kk = 0; kk < 16; kk++) {
            float4 a4 = *(const float4*)&As[kk][tr * 4];
            float4 b4 = *(const float4*)&Bs[kk][tc * 4];
            float a[4] = {a4.x, a4.y, a4.z, a4.w};
            float b[4] = {b4.x, b4.y, b4.z, b4.w};
#pragma unroll
            for (int i = 0; i < 4; i++)
#pragma unroll
                for (int j = 0; j < 4; j++) acc[i][j] += a[i] * b[j];
        }
    }
#pragma unroll
    for (int i = 0; i < 4; i++) {
        int r = row0 + tr * 4 + i;
        if (r >= M) continue;
#pragma unroll
        for (int j = 0; j < 4; j++) {
            int c = col0 + tc * 4 + j;
            if (c >= NCOLS) continue;
            float v = acc[i][j] + bias[c];
            if (RELU) v = fmaxf(v, 0.0f);
            C[(size_t)r * NCOLS + c] = v;
        }
    }
}

// ---------------- BN stats over N rows of hm[N,200] ----------------
__global__ void k_bnstat(const float* __restrict__ hm, float* __restrict__ gsum,
                         float* __restrict__ gsq) {
    int j = threadIdx.x;
    if (j >= MLPH) return;
    float s = 0.f, q = 0.f;
    for (int r = blockIdx.x; r < NN; r += gridDim.x) {
        float v = hm[(size_t)r * MLPH + j];
        s += v;
        q += v * v;
    }
    atomicAdd(&gsum[j], s);
    atomicAdd(&gsq[j], q);
}

// fold BN affine into Wo/bo:  Wo2[j][c] = scale[j]*Wo[j][c];  bo2[c] = bo[c] + sum_j shift[j]*Wo[j][c]
__global__ void k_bnfin(const float* __restrict__ gsum, const float* __restrict__ gsq,
                        const float* __restrict__ gamma, const float* __restrict__ beta,
                        const float* __restrict__ Wo, const float* __restrict__ bo,
                        float* __restrict__ Wo2, float* __restrict__ bo2) {
    __shared__ float sh[MLPH];
    int j = threadIdx.x;
    if (j < MLPH) {
        float mean = gsum[j] / (float)NN;
        float var = gsq[j] / (float)NN - mean * mean;
        float scale = gamma[j] * rsqrtf(var + 1e-5f);
        float shift = beta[j] - mean * scale;
        sh[j] = shift;
        Wo2[j * 2 + 0] = scale * Wo[j * 2 + 0];
        Wo2[j * 2 + 1] = scale * Wo[j * 2 + 1];
    }
    __syncthreads();
    if (j < 2) {
        float acc = bo[j];
        for (int t = 0; t < MLPH; t++) acc += sh[t] * Wo[t * 2 + j];
        bo2[j] = acc;
    }
}

// ---------------- final: out[n][c] = sum_j hm[n][j]*Wo2[j][c] + bo2[c], one wave per row ----------------
__global__ void k_out(const float* __restrict__ hm, const float* __restrict__ Wo2,
                      const float* __restrict__ bo2, float* __restrict__ out) {
    __shared__ float w[MLPH * 2];
    if (threadIdx.x < MLPH * 2) w[threadIdx.x] = Wo2[threadIdx.x];
    __syncthreads();
    int wid = (blockIdx.x * blockDim.x + threadIdx.x) >> 6;
    int lane = threadIdx.x & 63;
    if (wid >= NN) return;
    const float* row = hm + (size_t)wid * MLPH;
    float p0 = 0.f, p1 = 0.f;
    for (int j = lane; j < MLPH; j += 64) {
        float v = row[j];
        p0 += v * w[j * 2 + 0];
        p1 += v * w[j * 2 + 1];
    }
    for (int off = 32; off; off >>= 1) {
        p0 += __shfl_down(p0, off);
        p1 += __shfl_down(p1, off);
    }
    if (lane == 0) {
        out[wid * 2 + 0] = p0 + bo2[0];
        out[wid * 2 + 1] = p1 + bo2[1];
    }
}

extern "C" void kernel_launch(void* const* d_in, const int* in_sizes, int n_in,
                              void* d_out, int out_size, void* d_ws, size_t ws_size,
                              hipStream_t stream) {
    const float* features = (const float*)d_in[0];
    const int* src = (const int*)d_in[1];
    const int* dst = (const int*)d_in[2];
    const float* W1 = (const float*)d_in[3];
    const float* b1 = (const float*)d_in[4];
    const float* W2 = (const float*)d_in[5];
    const float* b2 = (const float*)d_in[6];
    const float* Wh = (const float*)d_in[7];
    const float* bh = (const float*)d_in[8];
    const float* gamma = (const float*)d_in[9];
    const float* beta = (const float*)d_in[10];
    const float* Wo = (const float*)d_in[11];
    const float* bo = (const float*)d_in[12];
    float* out = (float*)d_out;

    char* w = (char*)d_ws;
    auto alloc = [&](size_t bytes) -> void* {
        void* p = (void*)w;
        w += (bytes + 255) & ~(size_t)255;
        return p;
    };
    float* bufA = (float*)alloc((size_t)NN * DIM * 4);  // h_neigh / hm
    float* bufB = (float*)alloc((size_t)NN * DIM * 4);  // h1 / h2
    int* adj = (int*)alloc((size_t)NE * 4);
    int* counts = (int*)alloc((size_t)NN * 4);
    int* rowstart = (int*)alloc((size_t)(NN + 1) * 4);
    int* cursor = (int*)alloc((size_t)NN * 4);
    float* gsum = (float*)alloc(MLPH * 4);
    float* gsq = (float*)alloc(MLPH * 4);
    float* Wo2 = (float*)alloc(MLPH * 2 * 4);
    float* bo2 = (float*)alloc(2 * 4);

    hipMemsetAsync(counts, 0, (size_t)NN * 4, stream);
    hipMemsetAsync(gsum, 0, MLPH * 4, stream);
    hipMemsetAsync(gsq, 0, MLPH * 4, stream);

    // CSR build
    k_hist<<<(NE + 255) / 256, 256, 0, stream>>>(dst, counts);
    k_scan<<<1, 1024, 0, stream>>>(counts, rowstart, cursor);
    k_fill<<<(NE + 255) / 256, 256, 0, stream>>>(src, dst, cursor, adj);

    const int MB = (NN + 63) / 64;  // 782 row blocks

    // layer 1
    k_agg<<<NN, DIM, 0, stream>>>(features, rowstart, adj, counts, bufA);
    k_gemm<DIM, true><<<dim3(MB, DIM / 64), 256, 0, stream>>>(bufA, W1, b1, bufB, NN);
    // layer 2
    k_agg<<<NN, DIM, 0, stream>>>(bufB, rowstart, adj, counts, bufA);
    k_gemm<DIM, true><<<dim3(MB, DIM / 64), 256, 0, stream>>>(bufA, W2, b2, bufB, NN);
    // MLP hidden: hm = relu(h2 @ Wh + bh) -> reuse bufA
    k_gemm<MLPH, true><<<dim3(MB, (MLPH + 63) / 64), 256, 0, stream>>>(bufB, Wh, bh, bufA, NN);
    // BatchNorm stats + fold into Wo/bo
    k_bnstat<<<512, 256, 0, stream>>>(bufA, gsum, gsq);
    k_bnfin<<<1, 256, 0, stream>>>(gsum, gsq, gamma, beta, Wo, bo, Wo2, bo2);
    // output
    k_out<<<(NN * 64 + 511) / 512, 512, 0, stream>>>(bufA, Wo2, bo2, out);
}

// Round 2
// 754.071 us; speedup vs baseline: 2.3694x; 2.3694x over previous
//
#include <hip/hip_runtime.h>

#define NN 50000
#define NE 800000
#define DIM 512
#define MLPH 200

typedef __attribute__((ext_vector_type(8))) short short8;
typedef __attribute__((ext_vector_type(4))) float f32x4;

__device__ inline unsigned short f2bf(float f) {
    unsigned int u = __float_as_uint(f);
    unsigned int r = (u + 0x7fffu + ((u >> 16) & 1u)) >> 16;
    return (unsigned short)r;
}
__device__ inline float bflo(unsigned u) { return __uint_as_float(u << 16); }
__device__ inline float bfhi(unsigned u) { return __uint_as_float(u & 0xffff0000u); }
__device__ inline unsigned pack2(float a, float b) {
    return (unsigned)f2bf(a) | ((unsigned)f2bf(b) << 16);
}

// ---------------- CSR build ----------------
__global__ void k_hist(const int* __restrict__ dst, int* __restrict__ counts) {
    int e = blockIdx.x * blockDim.x + threadIdx.x;
    if (e < NE) atomicAdd(&counts[dst[e]], 1);
}

__global__ void k_scan(const int* __restrict__ counts, int* __restrict__ rowstart,
                       int* __restrict__ cursor) {
    __shared__ int sm[1024];
    __shared__ int carry;
    if (threadIdx.x == 0) carry = 0;
    __syncthreads();
    for (int base = 0; base < NN; base += 1024) {
        int i = base + threadIdx.x;
        int x = (i < NN) ? counts[i] : 0;
        sm[threadIdx.x] = x;
        __syncthreads();
        for (int off = 1; off < 1024; off <<= 1) {
            int v = (threadIdx.x >= (unsigned)off) ? sm[threadIdx.x - off] : 0;
            __syncthreads();
            sm[threadIdx.x] += v;
            __syncthreads();
        }
        int incl = sm[threadIdx.x];
        int excl = incl - x;
        if (i < NN) { rowstart[i] = carry + excl; cursor[i] = carry + excl; }
        __syncthreads();
        if (threadIdx.x == 1023) carry += incl;
        __syncthreads();
    }
    if (threadIdx.x == 0) rowstart[NN] = carry;
}

__global__ void k_fill(const int* __restrict__ src, const int* __restrict__ dst,
                       int* __restrict__ cursor, int* __restrict__ adj) {
    int e = blockIdx.x * blockDim.x + threadIdx.x;
    if (e < NE) {
        int p = atomicAdd(&cursor[dst[e]], 1);
        adj[p] = src[e];
    }
}

// ---------------- fp32 -> bf16 conversion (features) ----------------
__global__ void k_cvt(const float* __restrict__ in, ushort* __restrict__ out, int n4) {
    int i = blockIdx.x * blockDim.x + threadIdx.x;
    if (i >= n4) return;
    float4 v = *(const float4*)(in + (size_t)i * 4);
    ushort2 a{f2bf(v.x), f2bf(v.y)}, b{f2bf(v.z), f2bf(v.w)};
    *(ushort2*)(out + (size_t)i * 4) = a;
    *(ushort2*)(out + (size_t)i * 4 + 2) = b;
}

// ---------------- weight transpose + convert: W[K][N] f32 -> Wt[N][K] bf16 ----------------
__global__ void k_wt(const float* __restrict__ W, ushort* __restrict__ Wt, int ncols) {
    int i = blockIdx.x * blockDim.x + threadIdx.x;
    if (i >= ncols * 512) return;
    int n = i >> 9, k = i & 511;
    Wt[(size_t)n * 512 + k] = f2bf(W[(size_t)k * ncols + n]);
}

// ---------------- aggregation (bf16 in/out, fp32 accum): (sum_nbr + 2*self)/(deg+2) ----------------
__global__ __launch_bounds__(256) void k_agg_bf(const ushort* __restrict__ h,
                                                const int* __restrict__ rowstart,
                                                const int* __restrict__ adj,
                                                ushort* __restrict__ out) {
    int node = blockIdx.x * 4 + (threadIdx.x >> 6);
    int lane = threadIdx.x & 63;
    if (node >= NN) return;
    int s = rowstart[node], e = rowstart[node + 1];
    const size_t coff = (size_t)lane * 8;
    float acc[8];
    {
        uint4 v = *(const uint4*)(h + (size_t)node * DIM + coff);
        acc[0] = 2.f * bflo(v.x); acc[1] = 2.f * bfhi(v.x);
        acc[2] = 2.f * bflo(v.y); acc[3] = 2.f * bfhi(v.y);
        acc[4] = 2.f * bflo(v.z); acc[5] = 2.f * bfhi(v.z);
        acc[6] = 2.f * bflo(v.w); acc[7] = 2.f * bfhi(v.w);
    }
    for (int i = s; i < e; i++) {
        int nbr = adj[i];
        uint4 v = *(const uint4*)(h + (size_t)nbr * DIM + coff);
        acc[0] += bflo(v.x); acc[1] += bfhi(v.x);
        acc[2] += bflo(v.y); acc[3] += bfhi(v.y);
        acc[4] += bflo(v.z); acc[5] += bfhi(v.z);
        acc[6] += bflo(v.w); acc[7] += bfhi(v.w);
    }
    float inv = 1.0f / (float)(e - s + 2);
    uint4 o;
    o.x = pack2(acc[0] * inv, acc[1] * inv);
    o.y = pack2(acc[2] * inv, acc[3] * inv);
    o.z = pack2(acc[4] * inv, acc[5] * inv);
    o.w = pack2(acc[6] * inv, acc[7] * inv);
    *(uint4*)(out + (size_t)node * DIM + coff) = o;
}

// ---------------- bf16 MFMA GEMM: C[M,NCOLS] = relu(A[M,512] @ B + bias) ----------------
// A: bf16 row-major [M][512]; Bt: bf16 [NCOLS][512] (B transposed)
template <int NCOLS, bool OUT_BF16>
__global__ __launch_bounds__(256) void k_mgemm(const ushort* __restrict__ A,
                                               const ushort* __restrict__ Bt,
                                               const float* __restrict__ bias,
                                               float* __restrict__ Cf,
                                               ushort* __restrict__ Cb, int M) {
    constexpr int K = 512;
    constexpr int LDT = 40;  // padded LDS stride (elems)
    __shared__ ushort As[128 * LDT];
    __shared__ ushort Bs[128 * LDT];
    const int tid = threadIdx.x;
    const int wid = tid >> 6, lane = tid & 63;
    const int wm = wid >> 1, wn = wid & 1;
    const int row0 = blockIdx.x * 128, col0 = blockIdx.y * 128;
    const int srow = tid >> 2;  // 0..63
    const int sq = tid & 3;     // 0..3
    const int l15 = lane & 15, lk = (lane >> 4) * 8;

    f32x4 acc[4][4] = {};

    for (int k0 = 0; k0 < K; k0 += 32) {
        __syncthreads();
#pragma unroll
        for (int half = 0; half < 2; half++) {
            int r = srow + half * 64;
            int gr = row0 + r;
            uint4 va = {0, 0, 0, 0};
            if (gr < M) va = *(const uint4*)(A + (size_t)gr * K + k0 + sq * 8);
            *(uint4*)(As + r * LDT + sq * 8) = va;
            int gc = col0 + r;
            uint4 vb = {0, 0, 0, 0};
            if (NCOLS % 128 == 0 || gc < NCOLS)
                vb = *(const uint4*)(Bt + (size_t)gc * K + k0 + sq * 8);
            *(uint4*)(Bs + r * LDT + sq * 8) = vb;
        }
        __syncthreads();
        short8 a[4], b[4];
#pragma unroll
        for (int m = 0; m < 4; m++)
            a[m] = *(const short8*)(As + (wm * 64 + m * 16 + l15) * LDT + lk);
#pragma unroll
        for (int n = 0; n < 4; n++)
            b[n] = *(const short8*)(Bs + (wn * 64 + n * 16 + l15) * LDT + lk);
#pragma unroll
        for (int m = 0; m < 4; m++)
#pragma unroll
            for (int n = 0; n < 4; n++)
                acc[m][n] = __builtin_amdgcn_mfma_f32_16x16x32_bf16(a[m], b[n], acc[m][n], 0, 0, 0);
    }

    const int crow = row0 + wm * 64;
    const int ccol = col0 + wn * 64;
#pragma unroll
    for (int n = 0; n < 4; n++) {
        int c = ccol + n * 16 + l15;
        if (NCOLS % 128 != 0 && c >= NCOLS) continue;
        float bv = bias[c];
#pragma unroll
        for (int m = 0; m < 4; m++) {
#pragma unroll
            for (int i = 0; i < 4; i++) {
                int r = crow + m * 16 + (lane >> 4) * 4 + i;
                if (r >= M) continue;
                float v = fmaxf(acc[m][n][i] + bv, 0.0f);
                if (OUT_BF16) Cb[(size_t)r * NCOLS + c] = f2bf(v);
                else Cf[(size_t)r * NCOLS + c] = v;
            }
        }
    }
}

// ---------------- BN stats over N rows of hm[N,200] ----------------
__global__ void k_bnstat(const float* __restrict__ hm, float* __restrict__ gsum,
                         float* __restrict__ gsq) {
    int j = threadIdx.x;
    if (j >= MLPH) return;
    float s = 0.f, q = 0.f;
    for (int r = blockIdx.x; r < NN; r += gridDim.x) {
        float v = hm[(size_t)r * MLPH + j];
        s += v;
        q += v * v;
    }
    atomicAdd(&gsum[j], s);
    atomicAdd(&gsq[j], q);
}

__global__ void k_bnfin(const float* __restrict__ gsum, const float* __restrict__ gsq,
                        const float* __restrict__ gamma, const float* __restrict__ beta,
                        const float* __restrict__ Wo, const float* __restrict__ bo,
                        float* __restrict__ Wo2, float* __restrict__ bo2) {
    __shared__ float sh[MLPH];
    int j = threadIdx.x;
    if (j < MLPH) {
        float mean = gsum[j] / (float)NN;
        float var = gsq[j] / (float)NN - mean * mean;
        float scale = gamma[j] * rsqrtf(var + 1e-5f);
        float shift = beta[j] - mean * scale;
        sh[j] = shift;
        Wo2[j * 2 + 0] = scale * Wo[j * 2 + 0];
        Wo2[j * 2 + 1] = scale * Wo[j * 2 + 1];
    }
    __syncthreads();
    if (j < 2) {
        float acc = bo[j];
        for (int t = 0; t < MLPH; t++) acc += sh[t] * Wo[t * 2 + j];
        bo2[j] = acc;
    }
}

__global__ void k_out(const float* __restrict__ hm, const float* __restrict__ Wo2,
                      const float* __restrict__ bo2, float* __restrict__ out) {
    __shared__ float w[MLPH * 2];
    if (threadIdx.x < MLPH * 2) w[threadIdx.x] = Wo2[threadIdx.x];
    __syncthreads();
    int wid = (blockIdx.x * blockDim.x + threadIdx.x) >> 6;
    int lane = threadIdx.x & 63;
    if (wid >= NN) return;
    const float* row = hm + (size_t)wid * MLPH;
    float p0 = 0.f, p1 = 0.f;
    for (int j = lane; j < MLPH; j += 64) {
        float v = row[j];
        p0 += v * w[j * 2 + 0];
        p1 += v * w[j * 2 + 1];
    }
    for (int off = 32; off; off >>= 1) {
        p0 += __shfl_down(p0, off);
        p1 += __shfl_down(p1, off);
    }
    if (lane == 0) {
        out[wid * 2 + 0] = p0 + bo2[0];
        out[wid * 2 + 1] = p1 + bo2[1];
    }
}

extern "C" void kernel_launch(void* const* d_in, const int* in_sizes, int n_in,
                              void* d_out, int out_size, void* d_ws, size_t ws_size,
                              hipStream_t stream) {
    const float* features = (const float*)d_in[0];
    const int* src = (const int*)d_in[1];
    const int* dst = (const int*)d_in[2];
    const float* W1 = (const float*)d_in[3];
    const float* b1 = (const float*)d_in[4];
    const float* W2 = (const float*)d_in[5];
    const float* b2 = (const float*)d_in[6];
    const float* Wh = (const float*)d_in[7];
    const float* bh = (const float*)d_in[8];
    const float* gamma = (const float*)d_in[9];
    const float* beta = (const float*)d_in[10];
    const float* Wo = (const float*)d_in[11];
    const float* bo = (const float*)d_in[12];
    float* out = (float*)d_out;

    char* w = (char*)d_ws;
    auto alloc = [&](size_t bytes) -> void* {
        void* p = (void*)w;
        w += (bytes + 255) & ~(size_t)255;
        return p;
    };
    ushort* fb = (ushort*)alloc((size_t)NN * DIM * 2);   // features bf16; later h2 bf16
    ushort* ab = (ushort*)alloc((size_t)NN * DIM * 2);   // aggregation output bf16
    ushort* hb = (ushort*)alloc((size_t)NN * DIM * 2);   // h1 bf16
    float* hm = (float*)alloc((size_t)NN * MLPH * 4);    // MLP hidden fp32
    ushort* W1t = (ushort*)alloc((size_t)DIM * DIM * 2);
    ushort* W2t = (ushort*)alloc((size_t)DIM * DIM * 2);
    ushort* Wht = (ushort*)alloc((size_t)MLPH * DIM * 2);
    int* adj = (int*)alloc((size_t)NE * 4);
    int* counts = (int*)alloc((size_t)NN * 4);
    int* rowstart = (int*)alloc((size_t)(NN + 1) * 4);
    int* cursor = (int*)alloc((size_t)NN * 4);
    float* gsum = (float*)alloc(MLPH * 4);
    float* gsq = (float*)alloc(MLPH * 4);
    float* Wo2 = (float*)alloc(MLPH * 2 * 4);
    float* bo2 = (float*)alloc(2 * 4);

    hipMemsetAsync(counts, 0, (size_t)NN * 4, stream);
    hipMemsetAsync(gsum, 0, MLPH * 4, stream);
    hipMemsetAsync(gsq, 0, MLPH * 4, stream);

    // CSR build
    k_hist<<<(NE + 255) / 256, 256, 0, stream>>>(dst, counts);
    k_scan<<<1, 1024, 0, stream>>>(counts, rowstart, cursor);
    k_fill<<<(NE + 255) / 256, 256, 0, stream>>>(src, dst, cursor, adj);

    // conversions
    const int n4 = NN * DIM / 4;
    k_cvt<<<(n4 + 255) / 256, 256, 0, stream>>>(features, fb, n4);
    k_wt<<<(DIM * DIM + 255) / 256, 256, 0, stream>>>(W1, W1t, DIM);
    k_wt<<<(DIM * DIM + 255) / 256, 256, 0, stream>>>(W2, W2t, DIM);
    k_wt<<<(MLPH * DIM + 255) / 256, 256, 0, stream>>>(Wh, Wht, MLPH);

    const int MB = (NN + 127) / 128;  // 391

    // layer 1
    k_agg_bf<<<(NN + 3) / 4, 256, 0, stream>>>(fb, rowstart, adj, ab);
    k_mgemm<DIM, true><<<dim3(MB, DIM / 128), 256, 0, stream>>>(ab, W1t, b1, nullptr, hb, NN);
    // layer 2 (h2 -> fb, features no longer needed)
    k_agg_bf<<<(NN + 3) / 4, 256, 0, stream>>>(hb, rowstart, adj, ab);
    k_mgemm<DIM, true><<<dim3(MB, DIM / 128), 256, 0, stream>>>(ab, W2t, b2, nullptr, fb, NN);
    // MLP hidden: hm = relu(h2 @ Wh + bh), fp32 out
    k_mgemm<MLPH, false><<<dim3(MB, 2), 256, 0, stream>>>(fb, Wht, bh, hm, nullptr, NN);
    // BatchNorm stats + fold into Wo/bo
    k_bnstat<<<512, 256, 0, stream>>>(hm, gsum, gsq);
    k_bnfin<<<1, 256, 0, stream>>>(gsum, gsq, gamma, beta, Wo, bo, Wo2, bo2);
    // output
    k_out<<<(NN * 64 + 511) / 512, 512, 0, stream>>>(hm, Wo2, bo2, out);
}

// Round 3
// 630.483 us; speedup vs baseline: 2.8338x; 1.1960x over previous
//
#include <hip/hip_runtime.h>

#define NN 50000
#define NE 800000
#define DIM 512
#define MLPH 200

typedef __attribute__((ext_vector_type(8))) short short8;
typedef __attribute__((ext_vector_type(4))) float f32x4;

__device__ inline unsigned short f2bf(float f) {
    unsigned int u = __float_as_uint(f);
    unsigned int r = (u + 0x7fffu + ((u >> 16) & 1u)) >> 16;
    return (unsigned short)r;
}
__device__ inline float bflo(unsigned u) { return __uint_as_float(u << 16); }
__device__ inline float bfhi(unsigned u) { return __uint_as_float(u & 0xffff0000u); }
__device__ inline unsigned pack2(float a, float b) {
    return (unsigned)f2bf(a) | ((unsigned)f2bf(b) << 16);
}

// ---------------- CSR build ----------------
__global__ void k_hist(const int* __restrict__ dst, int* __restrict__ counts) {
    int e = blockIdx.x * blockDim.x + threadIdx.x;
    if (e < NE) atomicAdd(&counts[dst[e]], 1);
}

// phase A: per-block (256 elems) partial sums
__global__ void k_part(const int* __restrict__ counts, int* __restrict__ partial) {
    int t = threadIdx.x;
    int i = blockIdx.x * 256 + t;
    int x = (i < NN) ? counts[i] : 0;
#pragma unroll
    for (int off = 32; off; off >>= 1) x += __shfl_down(x, off);
    __shared__ int ws[4];
    if ((t & 63) == 0) ws[t >> 6] = x;
    __syncthreads();
    if (t == 0) partial[blockIdx.x] = ws[0] + ws[1] + ws[2] + ws[3];
}

// phase B: exclusive scan of 196 partials (single block), also rowstart[NN]=total
__global__ void k_scanp(int* __restrict__ partial, int* __restrict__ rowstart, int nb) {
    __shared__ int ws[4];
    int t = threadIdx.x;
    int x = (t < nb) ? partial[t] : 0;
    int v = x;
#pragma unroll
    for (int off = 1; off < 64; off <<= 1) {
        int u = __shfl_up(v, off);
        if ((t & 63) >= off) v += u;
    }
    if ((t & 63) == 63) ws[t >> 6] = v;
    __syncthreads();
    int add = 0;
#pragma unroll
    for (int w = 0; w < 4; w++)
        if (w < (t >> 6)) add += ws[w];
    if (t < nb) partial[t] = v - x + add;  // exclusive
    if (t == 255) rowstart[NN] = v + add;  // total == NE
}

// phase C: block-level exclusive scan + partial offset
__global__ void k_scan2(const int* __restrict__ counts, const int* __restrict__ pexcl,
                        int* __restrict__ rowstart, int* __restrict__ cursor) {
    __shared__ int ws[4];
    int t = threadIdx.x;
    int i = blockIdx.x * 256 + t;
    int x = (i < NN) ? counts[i] : 0;
    int v = x;
#pragma unroll
    for (int off = 1; off < 64; off <<= 1) {
        int u = __shfl_up(v, off);
        if ((t & 63) >= off) v += u;
    }
    if ((t & 63) == 63) ws[t >> 6] = v;
    __syncthreads();
    int add = 0;
#pragma unroll
    for (int w = 0; w < 4; w++)
        if (w < (t >> 6)) add += ws[w];
    if (i < NN) {
        int r = pexcl[blockIdx.x] + v - x + add;
        rowstart[i] = r;
        cursor[i] = r;
    }
}

__global__ void k_fill(const int* __restrict__ src, const int* __restrict__ dst,
                       int* __restrict__ cursor, int* __restrict__ adj) {
    int e = blockIdx.x * blockDim.x + threadIdx.x;
    if (e < NE) {
        int p = atomicAdd(&cursor[dst[e]], 1);
        adj[p] = src[e];
    }
}

// ---------------- fp32 -> bf16 conversion (features) ----------------
__global__ void k_cvt(const float* __restrict__ in, ushort* __restrict__ out, int n4) {
    int i = blockIdx.x * blockDim.x + threadIdx.x;
    if (i >= n4) return;
    float4 v = *(const float4*)(in + (size_t)i * 4);
    ushort2 a{f2bf(v.x), f2bf(v.y)}, b{f2bf(v.z), f2bf(v.w)};
    *(ushort2*)(out + (size_t)i * 4) = a;
    *(ushort2*)(out + (size_t)i * 4 + 2) = b;
}

// ---------------- all three weight transposes in one kernel ----------------
__global__ void k_wt3(const float* __restrict__ W1, const float* __restrict__ W2,
                      const float* __restrict__ Wh, ushort* __restrict__ W1t,
                      ushort* __restrict__ W2t, ushort* __restrict__ Wht) {
    int i = blockIdx.x * 256 + threadIdx.x;
    const int S1 = 512 * 512, S2 = 2 * 512 * 512, S3 = 2 * 512 * 512 + MLPH * 512;
    if (i < S1) {
        int n = i >> 9, k = i & 511;
        W1t[i] = f2bf(W1[(size_t)k * 512 + n]);
    } else if (i < S2) {
        int j = i - S1, n = j >> 9, k = j & 511;
        W2t[j] = f2bf(W2[(size_t)k * 512 + n]);
    } else if (i < S3) {
        int j = i - S2, n = j >> 9, k = j & 511;
        Wht[j] = f2bf(Wh[(size_t)k * MLPH + n]);
    }
}

// ---------------- aggregation (bf16 in/out, fp32 accum): (sum_nbr + 2*self)/(deg+2) ----------------
__device__ inline void addrow(float* acc, uint4 v) {
    acc[0] += bflo(v.x); acc[1] += bfhi(v.x);
    acc[2] += bflo(v.y); acc[3] += bfhi(v.y);
    acc[4] += bflo(v.z); acc[5] += bfhi(v.z);
    acc[6] += bflo(v.w); acc[7] += bfhi(v.w);
}

__global__ __launch_bounds__(256) void k_agg_bf(const ushort* __restrict__ h,
                                                const int* __restrict__ rowstart,
                                                const int* __restrict__ adj,
                                                ushort* __restrict__ out) {
    int node = blockIdx.x * 4 + (threadIdx.x >> 6);
    int lane = threadIdx.x & 63;
    if (node >= NN) return;
    int s = rowstart[node], e = rowstart[node + 1];
    const size_t coff = (size_t)lane * 8;
    float acc[8];
    {
        uint4 v = *(const uint4*)(h + (size_t)node * DIM + coff);
        acc[0] = 2.f * bflo(v.x); acc[1] = 2.f * bfhi(v.x);
        acc[2] = 2.f * bflo(v.y); acc[3] = 2.f * bfhi(v.y);
        acc[4] = 2.f * bflo(v.z); acc[5] = 2.f * bfhi(v.z);
        acc[6] = 2.f * bflo(v.w); acc[7] = 2.f * bfhi(v.w);
    }
    int i = s;
    int e4 = s + ((e - s) & ~3);
    for (; i < e4; i += 4) {
        int n0 = adj[i], n1 = adj[i + 1], n2 = adj[i + 2], n3 = adj[i + 3];
        uint4 v0 = *(const uint4*)(h + (size_t)n0 * DIM + coff);
        uint4 v1 = *(const uint4*)(h + (size_t)n1 * DIM + coff);
        uint4 v2 = *(const uint4*)(h + (size_t)n2 * DIM + coff);
        uint4 v3 = *(const uint4*)(h + (size_t)n3 * DIM + coff);
        addrow(acc, v0);
        addrow(acc, v1);
        addrow(acc, v2);
        addrow(acc, v3);
    }
    for (; i < e; i++) {
        int nbr = adj[i];
        uint4 v = *(const uint4*)(h + (size_t)nbr * DIM + coff);
        addrow(acc, v);
    }
    float inv = 1.0f / (float)(e - s + 2);
    uint4 o;
    o.x = pack2(acc[0] * inv, acc[1] * inv);
    o.y = pack2(acc[2] * inv, acc[3] * inv);
    o.z = pack2(acc[4] * inv, acc[5] * inv);
    o.w = pack2(acc[6] * inv, acc[7] * inv);
    *(uint4*)(out + (size_t)node * DIM + coff) = o;
}

// ---------------- bf16 MFMA GEMM: C[M,NCOLS] = relu(A[M,512] @ B + bias) ----------------
// A: bf16 row-major [M][512]; Bt: bf16 [NCOLS][512] (B transposed)
template <int NCOLS, bool OUT_BF16>
__global__ __launch_bounds__(256) void k_mgemm(const ushort* __restrict__ A,
                                               const ushort* __restrict__ Bt,
                                               const float* __restrict__ bias,
                                               float* __restrict__ Cf,
                                               ushort* __restrict__ Cb, int M) {
    constexpr int K = 512;
    constexpr int LDT = 40;  // padded LDS stride (elems): 2-way bank alias = free
    __shared__ ushort As[128 * LDT];
    __shared__ ushort Bs[128 * LDT];
    const int tid = threadIdx.x;
    const int wid = tid >> 6, lane = tid & 63;
    const int wm = wid >> 1, wn = wid & 1;
    const int row0 = blockIdx.x * 128, col0 = blockIdx.y * 128;
    const int srow = tid >> 2;  // 0..63
    const int sq = tid & 3;     // 0..3
    const int l15 = lane & 15, lk = (lane >> 4) * 8;

    f32x4 acc[4][4] = {};
    uint4 va[2], vb[2];

    auto loadAB = [&](int k0, uint4* a, uint4* b) {
#pragma unroll
        for (int half = 0; half < 2; half++) {
            int r = srow + half * 64;
            int gr = row0 + r;
            a[half] = uint4{0, 0, 0, 0};
            if (gr < M) a[half] = *(const uint4*)(A + (size_t)gr * K + k0 + sq * 8);
            int gc = col0 + r;
            b[half] = uint4{0, 0, 0, 0};
            if (NCOLS % 128 == 0 || gc < NCOLS)
                b[half] = *(const uint4*)(Bt + (size_t)gc * K + k0 + sq * 8);
        }
    };

    loadAB(0, va, vb);
    for (int k0 = 0; k0 < K; k0 += 32) {
        __syncthreads();
#pragma unroll
        for (int half = 0; half < 2; half++) {
            int r = srow + half * 64;
            *(uint4*)(As + r * LDT + sq * 8) = va[half];
            *(uint4*)(Bs + r * LDT + sq * 8) = vb[half];
        }
        uint4 na[2], nb[2];
        if (k0 + 32 < K) loadAB(k0 + 32, na, nb);
        __syncthreads();
        short8 a[4], b[4];
#pragma unroll
        for (int m = 0; m < 4; m++)
            a[m] = *(const short8*)(As + (wm * 64 + m * 16 + l15) * LDT + lk);
#pragma unroll
        for (int n = 0; n < 4; n++)
            b[n] = *(const short8*)(Bs + (wn * 64 + n * 16 + l15) * LDT + lk);
#pragma unroll
        for (int m = 0; m < 4; m++)
#pragma unroll
            for (int n = 0; n < 4; n++)
                acc[m][n] = __builtin_amdgcn_mfma_f32_16x16x32_bf16(a[m], b[n], acc[m][n], 0, 0, 0);
        if (k0 + 32 < K) {
#pragma unroll
            for (int half = 0; half < 2; half++) {
                va[half] = na[half];
                vb[half] = nb[half];
            }
        }
    }

    const int crow = row0 + wm * 64;
    const int ccol = col0 + wn * 64;
#pragma unroll
    for (int n = 0; n < 4; n++) {
        int c = ccol + n * 16 + l15;
        if (NCOLS % 128 != 0 && c >= NCOLS) continue;
        float bv = bias[c];
#pragma unroll
        for (int m = 0; m < 4; m++) {
#pragma unroll
            for (int i = 0; i < 4; i++) {
                int r = crow + m * 16 + (lane >> 4) * 4 + i;
                if (r >= M) continue;
                float v = fmaxf(acc[m][n][i] + bv, 0.0f);
                if (OUT_BF16) Cb[(size_t)r * NCOLS + c] = f2bf(v);
                else Cf[(size_t)r * NCOLS + c] = v;
            }
        }
    }
}

// ---------------- BN stats over N rows of hm[N,200] ----------------
__global__ void k_bnstat(const float* __restrict__ hm, float* __restrict__ gsum,
                         float* __restrict__ gsq) {
    int j = threadIdx.x;
    if (j >= MLPH) return;
    float s = 0.f, q = 0.f;
    for (int r = blockIdx.x; r < NN; r += gridDim.x) {
        float v = hm[(size_t)r * MLPH + j];
        s += v;
        q += v * v;
    }
    atomicAdd(&gsum[j], s);
    atomicAdd(&gsq[j], q);
}

__global__ void k_bnfin(const float* __restrict__ gsum, const float* __restrict__ gsq,
                        const float* __restrict__ gamma, const float* __restrict__ beta,
                        const float* __restrict__ Wo, const float* __restrict__ bo,
                        float* __restrict__ Wo2, float* __restrict__ bo2) {
    __shared__ float sh[MLPH];
    int j = threadIdx.x;
    if (j < MLPH) {
        float mean = gsum[j] / (float)NN;
        float var = gsq[j] / (float)NN - mean * mean;
        float scale = gamma[j] * rsqrtf(var + 1e-5f);
        float shift = beta[j] - mean * scale;
        sh[j] = shift;
        Wo2[j * 2 + 0] = scale * Wo[j * 2 + 0];
        Wo2[j * 2 + 1] = scale * Wo[j * 2 + 1];
    }
    __syncthreads();
    if (j < 2) {
        float acc = bo[j];
        for (int t = 0; t < MLPH; t++) acc += sh[t] * Wo[t * 2 + j];
        bo2[j] = acc;
    }
}

__global__ void k_out(const float* __restrict__ hm, const float* __restrict__ Wo2,
                      const float* __restrict__ bo2, float* __restrict__ out) {
    __shared__ float w[MLPH * 2];
    if (threadIdx.x < MLPH * 2) w[threadIdx.x] = Wo2[threadIdx.x];
    __syncthreads();
    int wid = (blockIdx.x * blockDim.x + threadIdx.x) >> 6;
    int lane = threadIdx.x & 63;
    if (wid >= NN) return;
    const float* row = hm + (size_t)wid * MLPH;
    float p0 = 0.f, p1 = 0.f;
    for (int j = lane; j < MLPH; j += 64) {
        float v = row[j];
        p0 += v * w[j * 2 + 0];
        p1 += v * w[j * 2 + 1];
    }
    for (int off = 32; off; off >>= 1) {
        p0 += __shfl_down(p0, off);
        p1 += __shfl_down(p1, off);
    }
    if (lane == 0) {
        out[wid * 2 + 0] = p0 + bo2[0];
        out[wid * 2 + 1] = p1 + bo2[1];
    }
}

extern "C" void kernel_launch(void* const* d_in, const int* in_sizes, int n_in,
                              void* d_out, int out_size, void* d_ws, size_t ws_size,
                              hipStream_t stream) {
    const float* features = (const float*)d_in[0];
    const int* src = (const int*)d_in[1];
    const int* dst = (const int*)d_in[2];
    const float* W1 = (const float*)d_in[3];
    const float* b1 = (const float*)d_in[4];
    const float* W2 = (const float*)d_in[5];
    const float* b2 = (const float*)d_in[6];
    const float* Wh = (const float*)d_in[7];
    const float* bh = (const float*)d_in[8];
    const float* gamma = (const float*)d_in[9];
    const float* beta = (const float*)d_in[10];
    const float* Wo = (const float*)d_in[11];
    const float* bo = (const float*)d_in[12];
    float* out = (float*)d_out;

    char* w = (char*)d_ws;
    auto alloc = [&](size_t bytes) -> void* {
        void* p = (void*)w;
        w += (bytes + 255) & ~(size_t)255;
        return p;
    };
    ushort* fb = (ushort*)alloc((size_t)NN * DIM * 2);   // features bf16; later h2 bf16
    ushort* ab = (ushort*)alloc((size_t)NN * DIM * 2);   // aggregation output bf16
    ushort* hb = (ushort*)alloc((size_t)NN * DIM * 2);   // h1 bf16
    float* hm = (float*)alloc((size_t)NN * MLPH * 4);    // MLP hidden fp32
    ushort* W1t = (ushort*)alloc((size_t)DIM * DIM * 2);
    ushort* W2t = (ushort*)alloc((size_t)DIM * DIM * 2);
    ushort* Wht = (ushort*)alloc((size_t)MLPH * DIM * 2);
    int* adj = (int*)alloc((size_t)NE * 4);
    int* counts = (int*)alloc((size_t)NN * 4);
    int* rowstart = (int*)alloc((size_t)(NN + 1) * 4);
    int* cursor = (int*)alloc((size_t)NN * 4);
    int* partial = (int*)alloc(256 * 4);
    float* gsum = (float*)alloc(MLPH * 4);
    float* gsq = (float*)alloc(MLPH * 4);
    float* Wo2 = (float*)alloc(MLPH * 2 * 4);
    float* bo2 = (float*)alloc(2 * 4);

    hipMemsetAsync(counts, 0, (size_t)NN * 4, stream);
    hipMemsetAsync(gsum, 0, MLPH * 4, stream);
    hipMemsetAsync(gsq, 0, MLPH * 4, stream);

    const int NB = (NN + 255) / 256;  // 196

    // CSR build (parallel scan)
    k_hist<<<(NE + 255) / 256, 256, 0, stream>>>(dst, counts);
    k_part<<<NB, 256, 0, stream>>>(counts, partial);
    k_scanp<<<1, 256, 0, stream>>>(partial, rowstart, NB);
    k_scan2<<<NB, 256, 0, stream>>>(counts, partial, rowstart, cursor);
    k_fill<<<(NE + 255) / 256, 256, 0, stream>>>(src, dst, cursor, adj);

    // conversions
    const int n4 = NN * DIM / 4;
    k_cvt<<<(n4 + 255) / 256, 256, 0, stream>>>(features, fb, n4);
    const int WT = 2 * 512 * 512 + MLPH * 512;
    k_wt3<<<(WT + 255) / 256, 256, 0, stream>>>(W1, W2, Wh, W1t, W2t, Wht);

    const int MB = (NN + 127) / 128;  // 391

    // layer 1
    k_agg_bf<<<(NN + 3) / 4, 256, 0, stream>>>(fb, rowstart, adj, ab);
    k_mgemm<DIM, true><<<dim3(MB, DIM / 128), 256, 0, stream>>>(ab, W1t, b1, nullptr, hb, NN);
    // layer 2 (h2 -> fb, features no longer needed)
    k_agg_bf<<<(NN + 3) / 4, 256, 0, stream>>>(hb, rowstart, adj, ab);
    k_mgemm<DIM, true><<<dim3(MB, DIM / 128), 256, 0, stream>>>(ab, W2t, b2, nullptr, fb, NN);
    // MLP hidden: hm = relu(h2 @ Wh + bh), fp32 out
    k_mgemm<MLPH, false><<<dim3(MB, 2), 256, 0, stream>>>(fb, Wht, bh, hm, nullptr, NN);
    // BatchNorm stats + fold into Wo/bo
    k_bnstat<<<512, 256, 0, stream>>>(hm, gsum, gsq);
    k_bnfin<<<1, 256, 0, stream>>>(gsum, gsq, gamma, beta, Wo, bo, Wo2, bo2);
    // output
    k_out<<<(NN * 64 + 511) / 512, 512, 0, stream>>>(hm, Wo2, bo2, out);
}